// Round 3
// baseline (111.440 us; speedup 1.0000x reference)
//
#include <hip/hip_runtime.h>
#include <hip/hip_bf16.h>

#define NBASIS 10
#define CDIM 16
#define DKDIM 8
#define JDIM 16

typedef _Float16 half8 __attribute__((ext_vector_type(8)));
typedef float floatx4 __attribute__((ext_vector_type(4)));

// adaptive load: f32 flag (wave-uniform) selects fp32 or bf16 interpretation
__device__ __forceinline__ float ldf(const void* p, int i, int f32) {
    if (f32) return ((const float*)p)[i];
    return __bfloat162float(((const __hip_bfloat16*)p)[i]);
}

// per-wave input-dtype detect: fp32 data read as bf16 shows implausible
// magnitudes in ~half the ushorts; bf16 N(0,1) shows none.
__device__ __forceinline__ int detect_f32(const void* x) {
    unsigned short b = ((const unsigned short*)x)[threadIdx.x & 63];
    float v = __uint_as_float(((unsigned int)b) << 16);
    bool bad = !(fabsf(v) < 1000.0f) || (v != 0.0f && fabsf(v) < 1e-15f);
    unsigned long long m = __ballot(bad);
    return (__popcll(m) >= 8) ? 1 : 0;
}

__device__ __forceinline__ const float* uniform_ptr(const float* p) {
    uint64_t v = (uint64_t)p;
    uint32_t lo = __builtin_amdgcn_readfirstlane((uint32_t)v);
    uint32_t hi = __builtin_amdgcn_readfirstlane((uint32_t)(v >> 32));
    return (const float*)(((uint64_t)hi << 32) | lo);
}

// ---------------- prep: W1 fp32, B-matrix fp16 fragment-packed, head=-1 ----
// (qbuf eliminated: q = x@Wq is computed per-edge inside edge_kernel's w1)
// Bpk flat index = ((nt*8 + ks)*64 + lane)*8 + j  (one dwordx4 per lane/frag)
//   kk = ks*32 + (lane>>4)*8 + j  -> c = kk>>4, jj = kk&15   (K = (c,j) = 256)
//   nn = nt*16 + (lane&15)        -> net = nn>>7, m = (nn>>3)&15, o = nn&7
__global__ __launch_bounds__(256) void prep_kernel(
    const void* __restrict__ x,
    const void* __restrict__ Wk1, const void* __restrict__ Wk2,
    const void* __restrict__ Wv1, const void* __restrict__ Wv2,
    float* __restrict__ w1k, float* __restrict__ w1v,
    _Float16* __restrict__ Bpk, int* __restrict__ head, int N)
{
    const int f32 = detect_f32(x);
    int i = blockIdx.x * 256 + threadIdx.x;
    if (i < 160) { w1k[i] = ldf(Wk1, i, f32); w1v[i] = ldf(Wv1, i, f32); }
    if (i < 65536) {
        int j = i & 7, lane = (i >> 3) & 63, ks = (i >> 9) & 7, nt = i >> 12;
        int kk = ks * 32 + (lane >> 4) * 8 + j;
        int nn = nt * 16 + (lane & 15);
        int c = kk >> 4, jj = kk & 15;
        int net = nn >> 7, m = (nn >> 3) & 15, o = nn & 7;
        float v = ldf(net ? Wv2 : Wk2, m * 2048 + c * 128 + jj * 8 + o, f32);
        Bpk[i] = (_Float16)v;
    }
    if (i < N) head[i] = -1;
}

// ---------------- edge kernel: geometry -> MFMA GEMM -> per-edge ev/v writes
// block = 256 thr = 4 waves = 64 edges. Wave w owns nt-quarter {4w..4w+3} for
// ALL 64 edges (row-tile pairs share each B fragment). D never hits LDS:
// per-lane h-contraction over nt (m = (2nt + col>>3)&15, o = col&7) then
// shfl_xor(8) merges m-halves; per-net partials combine via small LDS bufs.
// NO fp32 atomics: per-edge ev and v go to global with plain stores; one int
// atomicExch per edge (issued early, consumed late) prepends the edge onto
// its dst node's linked list (head/next). q = x[dst]@Wq computed in-kernel
// by wave 1 (scale (1/64)/sqrt(8) folded into q).
__global__ __launch_bounds__(256) void edge_kernel(
    const void* __restrict__ pos, const void* __restrict__ x,
    const void* __restrict__ Wq,
    const int* __restrict__ esrc, const int* __restrict__ edst,
    const float* __restrict__ w1k, const float* __restrict__ w1v,
    const _Float16* __restrict__ Bpk,
    int* __restrict__ head, int* __restrict__ next,
    float* __restrict__ evb, _Float16* __restrict__ vbuf, int E)
{
    __shared__ union {
        struct { float xs[64][17]; float sh[64][17]; } g;   // geometry phase
        _Float16 A[16384];            // [r][ks][lane][8] fp16 frags, 32 KB
        struct { float pk[2][64][9]; float pv[2][64][9]; } p; // partial k/v
    } u;
    __shared__ _Float16 hm_lds[64][34];  // [e][net*16 + m]
    __shared__ float cut_lds[64];
    __shared__ float q_lds[64][9];       // per-edge dst q, scale folded

    const int f32  = detect_f32(x);
    const int tid  = threadIdx.x;
    const int lane = tid & 63;
    const int w    = tid >> 6;
    const int q    = lane >> 4;
    const int e0   = blockIdx.x * 64;
    const int e_g  = e0 + lane;
    const int eidx = (e_g < E) ? e_g : (E - 1);
    const int s = esrc[eidx], d = edst[eidx];

    // linked-list prepend: issue atomic now, consume the old head much later
    int prev = -1;
    if (w == 0 && e_g < E) prev = atomicExch(&head[d], e_g);

    // ---- geometry (per-edge work split across the 4 waves) ----
    float vx = ldf(pos, s * 3 + 0, f32) - ldf(pos, d * 3 + 0, f32);
    float vy = ldf(pos, s * 3 + 1, f32) - ldf(pos, d * 3 + 1, f32);
    float vz = ldf(pos, s * 3 + 2, f32) - ldf(pos, d * 3 + 2, f32);
    float r2 = vx * vx + vy * vy + vz * vz;
    float r  = sqrtf(r2 + 1e-18f);          // ref: emb/cutoff radius has +eps

    if (w == 0) {            // spherical harmonics + cutoff
        float rsh = sqrtf(r2);              // ref: SH radius has no eps
        float inv = 1.0f / fmaxf(rsh, 1e-9f);
        float ux = vx * inv, uy = vy * inv, uz = vz * inv;
        const float s3   = 1.7320508075688772f;
        const float s5   = 2.23606797749979f;
        const float s15  = 3.872983346207417f;
        const float c358 = 2.091650066335189f;
        const float c218 = 1.6201851746019651f;
        const float s105 = 10.246950765959598f;
        const float s7h  = 1.3228756555322954f;
        float xx = ux * ux, yy = uy * uy, zz = uz * uz;
        float sh[16];
        sh[0] = 1.0f;
        sh[1] = s3 * ux; sh[2] = s3 * uy; sh[3] = s3 * uz;
        sh[4] = s15 * ux * uy;
        sh[5] = s15 * uy * uz;
        sh[6] = 0.5f * s5 * (3.0f * zz - 1.0f);
        sh[7] = s15 * ux * uz;
        sh[8] = 0.5f * s15 * (xx - yy);
        sh[9] = c358 * uy * (3.0f * xx - yy);
        sh[10] = s105 * ux * uy * uz;
        sh[11] = c218 * uy * (5.0f * zz - 1.0f);
        sh[12] = s7h * uz * (5.0f * zz - 3.0f);
        sh[13] = c218 * ux * (5.0f * zz - 1.0f);
        sh[14] = 0.5f * s105 * uz * (xx - yy);
        sh[15] = c358 * ux * (xx - 3.0f * yy);
        #pragma unroll
        for (int j = 0; j < 16; ++j) u.g.sh[lane][j] = sh[j];
        float tcut = 10.0f * (1.0f - r * (1.0f / 3.5f));
        cut_lds[lane] = (tcut > 0.0f) ? expf(-1.0f / tcut) : 0.0f;
    } else if (w == 1) {     // xs gather + per-edge q = x[dst]@Wq
        float xd[CDIM];
        #pragma unroll
        for (int c = 0; c < CDIM; ++c) {
            u.g.xs[lane][c] = ldf(x, s * CDIM + c, f32);
            xd[c] = ldf(x, d * CDIM + c, f32);
        }
        // scale: 1/64 (fcnet+norm) * 1/sqrt(8) (dk), folded into q
        const float qscale = (1.0f / 64.0f) * 0.35355339059327373f;
        #pragma unroll
        for (int o = 0; o < 8; ++o) {
            float acc = 0.0f;
            #pragma unroll
            for (int c = 0; c < CDIM; ++c)
                acc = fmaf(xd[c], ldf(Wq, c * DKDIM + o, f32), acc);
            q_lds[lane][o] = acc * qscale;
        }
    } else {                 // w=2: h_k, w=3: h_v (fp16 into hm_lds)
        const float* w1 = uniform_ptr((w == 2) ? w1k : w1v);
        const int off = (w == 2) ? 0 : 16;
        float emb[NBASIS];
        const float step = 3.5f / 11.0f;
        const float istep = 11.0f / 3.5f;
        const float coef = (float)(1.14136 * 7.38905609893065 * 3.1622776601683795);
        #pragma unroll
        for (int i = 0; i < NBASIS; ++i) {
            float uu = (r - step * (float)(i + 1)) * istep; uu *= uu;
            emb[i] = (uu < 1.0f) ? coef * expf(-1.0f / (1.0f - uu)) : 0.0f;
        }
        const float inv_s10 = 0.31622776601683794f;
        #pragma unroll
        for (int m = 0; m < 16; ++m) {
            float pre = 0.0f;
            #pragma unroll
            for (int nb = 0; nb < NBASIS; ++nb)
                pre = fmaf(emb[nb], w1[nb * 16 + m], pre);
            pre *= inv_s10;
            hm_lds[lane][off + m] = (_Float16)(pre / (1.0f + expf(-pre)));
        }
    }
    __syncthreads();

    // ---- A-frag build in regs (wave w -> row-tile r=w) ----
    half8 af[8];
    {
        const int erow = w * 16 + (lane & 15);
        const int coff = q >> 1, jj0 = (q & 1) * 8;
        #pragma unroll
        for (int ks = 0; ks < 8; ++ks) {
            float xsv = u.g.xs[erow][ks * 2 + coff];
            half8 a;
            #pragma unroll
            for (int j = 0; j < 8; ++j)
                a[j] = (_Float16)(xsv * u.g.sh[erow][jj0 + j]);
            af[ks] = a;
        }
    }
    __syncthreads();          // all g reads done -> overlay A
    {
        half8* Af = (half8*)u.A;
        #pragma unroll
        for (int ks = 0; ks < 8; ++ks)
            Af[(w * 8 + ks) * 64 + lane] = af[ks];
    }
    // consume the old head while the atomic result is long since in flight
    if (w == 0 && e_g < E) next[e_g] = prev;
    __syncthreads();

    // ---- GEMM over row-tile pairs + in-register h-contraction ----
    float part[16];           // [r][rr] partial k or v for edge r*16+q*4+rr
    #pragma unroll
    for (int i = 0; i < 16; ++i) part[i] = 0.0f;
    const int b3   = (lane >> 3) & 1;   // col>>3: which m-half this lane holds
    const int moff = (w >> 1) * 16;     // net offset into hm_lds (k=0, v=16)
    const half8* Af = (const half8*)u.A;
    const half8* Bf = (const half8*)Bpk;

    #pragma unroll
    for (int rp = 0; rp < 2; ++rp) {
        half8 a0[8], a1[8];
        #pragma unroll
        for (int ks = 0; ks < 8; ++ks) {
            a0[ks] = Af[((2 * rp)     * 8 + ks) * 64 + lane];
            a1[ks] = Af[((2 * rp + 1) * 8 + ks) * 64 + lane];
        }
        floatx4 acc0[4], acc1[4];
        #pragma unroll
        for (int l = 0; l < 4; ++l) {
            acc0[l] = (floatx4){0.f, 0.f, 0.f, 0.f};
            acc1[l] = (floatx4){0.f, 0.f, 0.f, 0.f};
        }
        #pragma unroll
        for (int l = 0; l < 4; ++l) {
            const int nt = 4 * w + l;
            #pragma unroll
            for (int ks = 0; ks < 8; ++ks) {
                half8 b = Bf[(nt * 8 + ks) * 64 + lane];
                acc0[l] = __builtin_amdgcn_mfma_f32_16x16x32_f16(a0[ks], b, acc0[l], 0, 0, 0);
                acc1[l] = __builtin_amdgcn_mfma_f32_16x16x32_f16(a1[ks], b, acc1[l], 0, 0, 0);
            }
        }
        #pragma unroll
        for (int l = 0; l < 4; ++l) {
            const int m = ((4 * w + l) * 2 + b3) & 15;
            #pragma unroll
            for (int rr = 0; rr < 4; ++rr) {
                const int er = q * 4 + rr;
                part[(2 * rp) * 4 + rr] +=
                    (float)hm_lds[(2 * rp) * 16 + er][moff + m] * acc0[l][rr];
                part[(2 * rp + 1) * 4 + rr] +=
                    (float)hm_lds[(2 * rp + 1) * 16 + er][moff + m] * acc1[l][rr];
            }
        }
    }
    // merge the two m-halves (lanes col and col^8 hold same (e,o))
    #pragma unroll
    for (int i = 0; i < 16; ++i) part[i] += __shfl_xor(part[i], 8, 64);

    __syncthreads();          // A reads done -> overlay partial buffers
    if (b3 == 0) {
        const int o = lane & 7;
        #pragma unroll
        for (int i = 0; i < 16; ++i) {
            const int e = (i >> 2) * 16 + q * 4 + (i & 3);
            if (w < 2) u.p.pk[w][e][o] = part[i];
            else       u.p.pv[w - 2][e][o] = part[i];
        }
    }
    __syncthreads();

    // ---- per-edge ev = cutoff * exp(logit), plain store (no atomics) ----
    if (tid < 64) {
        float logit = 0.0f;
        #pragma unroll
        for (int o = 0; o < 8; ++o) {
            float kv = u.p.pk[0][tid][o] + u.p.pk[1][tid][o];
            logit = fmaf(q_lds[tid][o], kv, logit);   // scale pre-folded in q
        }
        if (e0 + tid < E)
            evb[e0 + tid] = cut_lds[tid] * expf(logit);   // unstabilized, matches ref
    }

    // ---- per-edge v (1/64 folded), packed fp16x2 stores ----
    {
        const int el = tid & 63, op = tid >> 6;
        if (e0 + el < E) {
            float v0 = u.p.pv[0][el][2 * op]     + u.p.pv[1][el][2 * op];
            float v1 = u.p.pv[0][el][2 * op + 1] + u.p.pv[1][el][2 * op + 1];
            union { _Float16 h[2]; unsigned int b; } pk2;
            pk2.h[0] = (_Float16)(v0 * (1.0f / 64.0f));
            pk2.h[1] = (_Float16)(v1 * (1.0f / 64.0f));
            ((unsigned int*)vbuf)[(size_t)(e0 + el) * 4 + op] = pk2.b;
        }
    }
}

// ---------------- node kernel: single walk of the dst linked list.
// z = sum ev and s = sum sqrt(ev)*v accumulated together; out = s / sqrt(z).
// 8 threads per node (o = 0..7) walk the same list -> loads broadcast.
__global__ __launch_bounds__(256) void node_kernel(
    const float* __restrict__ evb, const _Float16* __restrict__ vbuf,
    const int* __restrict__ head, const int* __restrict__ next,
    void* __restrict__ out, const void* __restrict__ x, int n8)
{
    const int f32 = detect_f32(x);   // full-wave ballot before any divergence
    int i = blockIdx.x * 256 + threadIdx.x;
    if (i >= n8) return;
    const int n = i >> 3, o = i & 7;
    float z = 0.0f, acc = 0.0f;
    for (int e = head[n]; e >= 0; e = next[e]) {
        float ev = evb[e];
        z += ev;
        acc += sqrtf(ev) * (float)vbuf[(size_t)e * 8 + o];
    }
    z = (z == 0.0f) ? 1.0f : z;
    float val = acc / sqrtf(z);
    if (f32) ((float*)out)[i] = val;
    else ((__hip_bfloat16*)out)[i] = __float2bfloat16(val);
}

extern "C" void kernel_launch(void* const* d_in, const int* in_sizes, int n_in,
                              void* d_out, int out_size, void* d_ws, size_t ws_size,
                              hipStream_t stream)
{
    const void* pos = d_in[0];
    const void* x   = d_in[1];
    const void* Wq  = d_in[2];
    const void* Wk1 = d_in[3];
    const void* Wk2 = d_in[4];
    const void* Wv1 = d_in[5];
    const void* Wv2 = d_in[6];
    const int* esrc = (const int*)d_in[7];
    const int* edst = (const int*)d_in[8];
    const int N = in_sizes[1] / CDIM;
    const int E = in_sizes[7];

    // workspace layout (Bpk first for 16B alignment of half8 loads)
    _Float16* Bpk = (_Float16*)d_ws;                       // 65536 fp16
    float* w1k  = (float*)(Bpk + 65536);                   // 160
    float* w1v  = w1k + 160;                               // 160
    float* evb  = w1v + 160;                               // E
    _Float16* vbuf = (_Float16*)(evb + E);                 // E*8 fp16
    int*   head = (int*)(vbuf + (size_t)E * 8);            // N
    int*   next = head + N;                                // E

    int prep_threads = N > 65536 ? N : 65536;
    int prep_blocks = (prep_threads + 255) / 256;
    prep_kernel<<<prep_blocks, 256, 0, stream>>>(x, Wk1, Wk2, Wv1, Wv2,
                                                 w1k, w1v, Bpk, head, N);

    int edge_blocks = (E + 63) / 64;
    edge_kernel<<<edge_blocks, 256, 0, stream>>>(pos, x, Wq, esrc, edst,
                                                 w1k, w1v, Bpk,
                                                 head, next, evb, vbuf, E);

    node_kernel<<<(N * 8 + 255) / 256, 256, 0, stream>>>(
        evb, vbuf, head, next, d_out, x, N * 8);
}

// Round 4
// 100.322 us; speedup vs baseline: 1.1108x; 1.1108x over previous
//
#include <hip/hip_runtime.h>
#include <hip/hip_bf16.h>

#define NBASIS 10
#define CDIM 16
#define DKDIM 8
#define JDIM 16

typedef _Float16 half8 __attribute__((ext_vector_type(8)));
typedef float floatx4 __attribute__((ext_vector_type(4)));
typedef unsigned short ushort8 __attribute__((ext_vector_type(8)));

// adaptive load: f32 flag (wave-uniform) selects fp32 or bf16 interpretation
__device__ __forceinline__ float ldf(const void* p, int i, int f32) {
    if (f32) return ((const float*)p)[i];
    return __bfloat162float(((const __hip_bfloat16*)p)[i]);
}

// per-wave input-dtype detect: fp32 data read as bf16 shows implausible
// magnitudes in ~half the ushorts; bf16 N(0,1) shows none.
__device__ __forceinline__ int detect_f32(const void* x) {
    unsigned short b = ((const unsigned short*)x)[threadIdx.x & 63];
    float v = __uint_as_float(((unsigned int)b) << 16);
    bool bad = !(fabsf(v) < 1000.0f) || (v != 0.0f && fabsf(v) < 1e-15f);
    unsigned long long m = __ballot(bad);
    return (__popcll(m) >= 8) ? 1 : 0;
}

__device__ __forceinline__ const float* uniform_ptr(const float* p) {
    uint64_t v = (uint64_t)p;
    uint32_t lo = __builtin_amdgcn_readfirstlane((uint32_t)v);
    uint32_t hi = __builtin_amdgcn_readfirstlane((uint32_t)(v >> 32));
    return (const float*)(((uint64_t)hi << 32) | lo);
}

// vectorized 16-channel row load (rows are 16B-aligned in both dtypes)
__device__ __forceinline__ void load_row16(const void* x, int n, int f32,
                                           float* dst) {
    if (f32) {
        const floatx4* r = (const floatx4*)((const float*)x + (size_t)n * CDIM);
        #pragma unroll
        for (int t = 0; t < 4; ++t) {
            floatx4 v4 = r[t];
            dst[t * 4 + 0] = v4[0]; dst[t * 4 + 1] = v4[1];
            dst[t * 4 + 2] = v4[2]; dst[t * 4 + 3] = v4[3];
        }
    } else {
        const ushort8* r = (const ushort8*)((const unsigned short*)x + (size_t)n * CDIM);
        #pragma unroll
        for (int t = 0; t < 2; ++t) {
            ushort8 v8 = r[t];
            #pragma unroll
            for (int j = 0; j < 8; ++j)
                dst[t * 8 + j] = __uint_as_float(((unsigned int)v8[j]) << 16);
        }
    }
}

// ---------------- prep: W1 fp32, B-matrix fp16 fragment-packed, q=x@Wq
// (logit scale folded), head=-1 ---------------------------------------------
// Bpk flat index = ((nt*8 + ks)*64 + lane)*8 + j  (one dwordx4 per lane/frag)
//   kk = ks*32 + (lane>>4)*8 + j  -> c = kk>>4, jj = kk&15   (K = (c,j) = 256)
//   nn = nt*16 + (lane&15)        -> net = nn>>7, m = (nn>>3)&15, o = nn&7
__global__ __launch_bounds__(256) void prep_kernel(
    const void* __restrict__ x, const void* __restrict__ Wq,
    const void* __restrict__ Wk1, const void* __restrict__ Wk2,
    const void* __restrict__ Wv1, const void* __restrict__ Wv2,
    float* __restrict__ w1k, float* __restrict__ w1v,
    float* __restrict__ qbuf, _Float16* __restrict__ Bpk,
    int* __restrict__ head, int N)
{
    const int f32 = detect_f32(x);
    int i = blockIdx.x * 256 + threadIdx.x;
    if (i < 160) { w1k[i] = ldf(Wk1, i, f32); w1v[i] = ldf(Wv1, i, f32); }
    if (i < 65536) {
        int j = i & 7, lane = (i >> 3) & 63, ks = (i >> 9) & 7, nt = i >> 12;
        int kk = ks * 32 + (lane >> 4) * 8 + j;
        int nn = nt * 16 + (lane & 15);
        int c = kk >> 4, jj = kk & 15;
        int net = nn >> 7, m = (nn >> 3) & 15, o = nn & 7;
        float v = ldf(net ? Wv2 : Wk2, m * 2048 + c * 128 + jj * 8 + o, f32);
        Bpk[i] = (_Float16)v;
    }
    if (i < N) head[i] = -1;
    if (i < N * 8) {
        int n = i >> 3, o = i & 7;
        float acc = 0.0f;
        #pragma unroll
        for (int c = 0; c < CDIM; ++c)
            acc = fmaf(ldf(x, n * CDIM + c, f32), ldf(Wq, c * DKDIM + o, f32), acc);
        // scale: 1/64 (fcnet+norm) * 1/sqrt(8) (dk), folded here
        qbuf[i] = acc * ((1.0f / 64.0f) * 0.35355339059327373f);
    }
}

// ---------------- edge kernel: geometry -> MFMA GEMM -> per-edge ev/v writes
// block = 256 thr = 4 waves = 64 edges. Wave w owns nt-quarter {4w..4w+3} for
// ALL 64 edges (row-tile pairs share each B fragment). D never hits LDS:
// per-lane h-contraction over nt (m = (2nt + col>>3)&15, o = col&7) then
// shfl_xor(8) merges m-halves; per-net partials combine via small LDS bufs.
// NO fp32 atomics: per-edge ev and v go to global with plain stores; one int
// atomicExch per edge (issued early, consumed late) prepends the edge onto
// its dst node's linked list (head/next).
__global__ __launch_bounds__(256) void edge_kernel(
    const void* __restrict__ pos, const void* __restrict__ x,
    const int* __restrict__ esrc, const int* __restrict__ edst,
    const float* __restrict__ w1k, const float* __restrict__ w1v,
    const float* __restrict__ qbuf, const _Float16* __restrict__ Bpk,
    int* __restrict__ head, int* __restrict__ next,
    float* __restrict__ evb, _Float16* __restrict__ vbuf, int E)
{
    __shared__ union {
        struct { float xs[64][17]; float sh[64][17]; } g;   // geometry phase
        _Float16 A[16384];            // [r][ks][lane][8] fp16 frags, 32 KB
        struct { float pk[2][64][9]; float pv[2][64][9]; } p; // partial k/v
    } u;
    __shared__ _Float16 hm_lds[64][34];  // [e][net*16 + m]
    __shared__ float cut_lds[64];
    __shared__ int   d_lds[64];

    const int f32  = detect_f32(x);
    const int tid  = threadIdx.x;
    const int lane = tid & 63;
    const int w    = tid >> 6;
    const int q    = lane >> 4;
    const int e0   = blockIdx.x * 64;
    const int e_g  = e0 + lane;
    const int eidx = (e_g < E) ? e_g : (E - 1);
    const int s = esrc[eidx], d = edst[eidx];

    // linked-list prepend: issue atomic now, consume the old head much later
    int prev = -1;
    if (w == 0 && e_g < E) prev = atomicExch(&head[d], e_g);

    // ---- geometry (per-edge work split across the 4 waves) ----
    float vx = ldf(pos, s * 3 + 0, f32) - ldf(pos, d * 3 + 0, f32);
    float vy = ldf(pos, s * 3 + 1, f32) - ldf(pos, d * 3 + 1, f32);
    float vz = ldf(pos, s * 3 + 2, f32) - ldf(pos, d * 3 + 2, f32);
    float r2 = vx * vx + vy * vy + vz * vz;
    float r  = sqrtf(r2 + 1e-18f);          // ref: emb/cutoff radius has +eps

    if (w == 0) {            // spherical harmonics + cutoff + dst
        float rsh = sqrtf(r2);              // ref: SH radius has no eps
        float inv = 1.0f / fmaxf(rsh, 1e-9f);
        float ux = vx * inv, uy = vy * inv, uz = vz * inv;
        const float s3   = 1.7320508075688772f;
        const float s5   = 2.23606797749979f;
        const float s15  = 3.872983346207417f;
        const float c358 = 2.091650066335189f;
        const float c218 = 1.6201851746019651f;
        const float s105 = 10.246950765959598f;
        const float s7h  = 1.3228756555322954f;
        float xx = ux * ux, yy = uy * uy, zz = uz * uz;
        float sh[16];
        sh[0] = 1.0f;
        sh[1] = s3 * ux; sh[2] = s3 * uy; sh[3] = s3 * uz;
        sh[4] = s15 * ux * uy;
        sh[5] = s15 * uy * uz;
        sh[6] = 0.5f * s5 * (3.0f * zz - 1.0f);
        sh[7] = s15 * ux * uz;
        sh[8] = 0.5f * s15 * (xx - yy);
        sh[9] = c358 * uy * (3.0f * xx - yy);
        sh[10] = s105 * ux * uy * uz;
        sh[11] = c218 * uy * (5.0f * zz - 1.0f);
        sh[12] = s7h * uz * (5.0f * zz - 3.0f);
        sh[13] = c218 * ux * (5.0f * zz - 1.0f);
        sh[14] = 0.5f * s105 * uz * (xx - yy);
        sh[15] = c358 * ux * (xx - 3.0f * yy);
        #pragma unroll
        for (int j = 0; j < 16; ++j) u.g.sh[lane][j] = sh[j];
        float tcut = 10.0f * (1.0f - r * (1.0f / 3.5f));
        cut_lds[lane] = (tcut > 0.0f) ? expf(-1.0f / tcut) : 0.0f;
        d_lds[lane] = d;
    } else if (w == 1) {     // xs gather, vectorized 16B loads
        float row[CDIM];
        load_row16(x, s, f32, row);
        #pragma unroll
        for (int c = 0; c < CDIM; ++c) u.g.xs[lane][c] = row[c];
    } else {                 // w=2: h_k, w=3: h_v (fp16 into hm_lds)
        const float* w1 = uniform_ptr((w == 2) ? w1k : w1v);
        const int off = (w == 2) ? 0 : 16;
        float emb[NBASIS];
        const float step = 3.5f / 11.0f;
        const float istep = 11.0f / 3.5f;
        const float coef = (float)(1.14136 * 7.38905609893065 * 3.1622776601683795);
        #pragma unroll
        for (int i = 0; i < NBASIS; ++i) {
            float uu = (r - step * (float)(i + 1)) * istep; uu *= uu;
            emb[i] = (uu < 1.0f) ? coef * expf(-1.0f / (1.0f - uu)) : 0.0f;
        }
        const float inv_s10 = 0.31622776601683794f;
        #pragma unroll
        for (int m = 0; m < 16; ++m) {
            float pre = 0.0f;
            #pragma unroll
            for (int nb = 0; nb < NBASIS; ++nb)
                pre = fmaf(emb[nb], w1[nb * 16 + m], pre);
            pre *= inv_s10;
            hm_lds[lane][off + m] = (_Float16)(pre / (1.0f + expf(-pre)));
        }
    }
    __syncthreads();

    // ---- A-frag build in regs (wave w -> row-tile r=w) ----
    half8 af[8];
    {
        const int erow = w * 16 + (lane & 15);
        const int coff = q >> 1, jj0 = (q & 1) * 8;
        #pragma unroll
        for (int ks = 0; ks < 8; ++ks) {
            float xsv = u.g.xs[erow][ks * 2 + coff];
            half8 a;
            #pragma unroll
            for (int j = 0; j < 8; ++j)
                a[j] = (_Float16)(xsv * u.g.sh[erow][jj0 + j]);
            af[ks] = a;
        }
    }
    __syncthreads();          // all g reads done -> overlay A
    {
        half8* Af = (half8*)u.A;
        #pragma unroll
        for (int ks = 0; ks < 8; ++ks)
            Af[(w * 8 + ks) * 64 + lane] = af[ks];
    }
    // consume the old head while the atomic result is long since in flight
    if (w == 0 && e_g < E) next[e_g] = prev;
    __syncthreads();

    // ---- GEMM over row-tile pairs + in-register h-contraction ----
    float part[16];           // [r][rr] partial k or v for edge r*16+q*4+rr
    #pragma unroll
    for (int i = 0; i < 16; ++i) part[i] = 0.0f;
    const int b3   = (lane >> 3) & 1;   // col>>3: which m-half this lane holds
    const int moff = (w >> 1) * 16;     // net offset into hm_lds (k=0, v=16)
    const half8* Af = (const half8*)u.A;
    const half8* Bf = (const half8*)Bpk;

    #pragma unroll
    for (int rp = 0; rp < 2; ++rp) {
        half8 a0[8], a1[8];
        #pragma unroll
        for (int ks = 0; ks < 8; ++ks) {
            a0[ks] = Af[((2 * rp)     * 8 + ks) * 64 + lane];
            a1[ks] = Af[((2 * rp + 1) * 8 + ks) * 64 + lane];
        }
        floatx4 acc0[4], acc1[4];
        #pragma unroll
        for (int l = 0; l < 4; ++l) {
            acc0[l] = (floatx4){0.f, 0.f, 0.f, 0.f};
            acc1[l] = (floatx4){0.f, 0.f, 0.f, 0.f};
        }
        #pragma unroll
        for (int l = 0; l < 4; ++l) {
            const int nt = 4 * w + l;
            #pragma unroll
            for (int ks = 0; ks < 8; ++ks) {
                half8 b = Bf[(nt * 8 + ks) * 64 + lane];
                acc0[l] = __builtin_amdgcn_mfma_f32_16x16x32_f16(a0[ks], b, acc0[l], 0, 0, 0);
                acc1[l] = __builtin_amdgcn_mfma_f32_16x16x32_f16(a1[ks], b, acc1[l], 0, 0, 0);
            }
        }
        #pragma unroll
        for (int l = 0; l < 4; ++l) {
            const int m = ((4 * w + l) * 2 + b3) & 15;
            #pragma unroll
            for (int rr = 0; rr < 4; ++rr) {
                const int er = q * 4 + rr;
                part[(2 * rp) * 4 + rr] +=
                    (float)hm_lds[(2 * rp) * 16 + er][moff + m] * acc0[l][rr];
                part[(2 * rp + 1) * 4 + rr] +=
                    (float)hm_lds[(2 * rp + 1) * 16 + er][moff + m] * acc1[l][rr];
            }
        }
    }
    // merge the two m-halves (lanes col and col^8 hold same (e,o))
    #pragma unroll
    for (int i = 0; i < 16; ++i) part[i] += __shfl_xor(part[i], 8, 64);

    __syncthreads();          // A reads done -> overlay partial buffers
    if (b3 == 0) {
        const int o = lane & 7;
        #pragma unroll
        for (int i = 0; i < 16; ++i) {
            const int e = (i >> 2) * 16 + q * 4 + (i & 3);
            if (w < 2) u.p.pk[w][e][o] = part[i];
            else       u.p.pv[w - 2][e][o] = part[i];
        }
    }
    __syncthreads();

    // ---- per-edge ev = cutoff * exp(logit), plain store (no atomics) ----
    if (tid < 64) {
        const int dd = d_lds[tid];
        float logit = 0.0f;
        #pragma unroll
        for (int o = 0; o < 8; ++o) {
            float kv = u.p.pk[0][tid][o] + u.p.pk[1][tid][o];
            logit = fmaf(qbuf[(size_t)dd * 8 + o], kv, logit);  // scale folded
        }
        if (e0 + tid < E)
            evb[e0 + tid] = cut_lds[tid] * expf(logit);   // unstabilized, matches ref
    }

    // ---- per-edge v (1/64 folded), packed fp16x2 stores ----
    {
        const int el = tid & 63, op = tid >> 6;
        if (e0 + el < E) {
            float v0 = u.p.pv[0][el][2 * op]     + u.p.pv[1][el][2 * op];
            float v1 = u.p.pv[0][el][2 * op + 1] + u.p.pv[1][el][2 * op + 1];
            union { _Float16 h[2]; unsigned int b; } pk2;
            pk2.h[0] = (_Float16)(v0 * (1.0f / 64.0f));
            pk2.h[1] = (_Float16)(v1 * (1.0f / 64.0f));
            ((unsigned int*)vbuf)[(size_t)(e0 + el) * 4 + op] = pk2.b;
        }
    }
}

// ---------------- node kernel: single walk of the dst linked list.
// z = sum ev and s = sum sqrt(ev)*v accumulated together; out = s / sqrt(z).
// 8 threads per node (o = 0..7) walk the same list -> loads broadcast.
__global__ __launch_bounds__(256) void node_kernel(
    const float* __restrict__ evb, const _Float16* __restrict__ vbuf,
    const int* __restrict__ head, const int* __restrict__ next,
    void* __restrict__ out, const void* __restrict__ x, int n8)
{
    const int f32 = detect_f32(x);   // full-wave ballot before any divergence
    int i = blockIdx.x * 256 + threadIdx.x;
    if (i >= n8) return;
    const int n = i >> 3, o = i & 7;
    float z = 0.0f, acc = 0.0f;
    for (int e = head[n]; e >= 0; e = next[e]) {
        float ev = evb[e];
        z += ev;
        acc += sqrtf(ev) * (float)vbuf[(size_t)e * 8 + o];
    }
    z = (z == 0.0f) ? 1.0f : z;
    float val = acc / sqrtf(z);
    if (f32) ((float*)out)[i] = val;
    else ((__hip_bfloat16*)out)[i] = __float2bfloat16(val);
}

extern "C" void kernel_launch(void* const* d_in, const int* in_sizes, int n_in,
                              void* d_out, int out_size, void* d_ws, size_t ws_size,
                              hipStream_t stream)
{
    const void* pos = d_in[0];
    const void* x   = d_in[1];
    const void* Wq  = d_in[2];
    const void* Wk1 = d_in[3];
    const void* Wk2 = d_in[4];
    const void* Wv1 = d_in[5];
    const void* Wv2 = d_in[6];
    const int* esrc = (const int*)d_in[7];
    const int* edst = (const int*)d_in[8];
    const int N = in_sizes[1] / CDIM;
    const int E = in_sizes[7];

    // workspace layout (Bpk first for 16B alignment of half8 loads)
    _Float16* Bpk = (_Float16*)d_ws;                       // 65536 fp16
    float* w1k  = (float*)(Bpk + 65536);                   // 160
    float* w1v  = w1k + 160;                               // 160
    float* qbuf = w1v + 160;                               // N*8
    float* evb  = qbuf + (size_t)N * 8;                    // E
    _Float16* vbuf = (_Float16*)(evb + E);                 // E*8 fp16
    int*   head = (int*)(vbuf + (size_t)E * 8);            // N
    int*   next = head + N;                                // E

    int prep_threads = N * 8 > 65536 ? N * 8 : 65536;
    int prep_blocks = (prep_threads + 255) / 256;
    prep_kernel<<<prep_blocks, 256, 0, stream>>>(x, Wq, Wk1, Wk2, Wv1, Wv2,
                                                 w1k, w1v, qbuf, Bpk, head, N);

    int edge_blocks = (E + 63) / 64;
    edge_kernel<<<edge_blocks, 256, 0, stream>>>(pos, x, esrc, edst,
                                                 w1k, w1v, qbuf, Bpk,
                                                 head, next, evb, vbuf, E);

    node_kernel<<<(N * 8 + 255) / 256, 256, 0, stream>>>(
        evb, vbuf, head, next, d_out, x, N * 8);
}

// Round 5
// 96.225 us; speedup vs baseline: 1.1581x; 1.0426x over previous
//
#include <hip/hip_runtime.h>
#include <hip/hip_bf16.h>

#define NBASIS 10
#define CDIM 16
#define DKDIM 8
#define JDIM 16

typedef _Float16 half8 __attribute__((ext_vector_type(8)));
typedef float floatx4 __attribute__((ext_vector_type(4)));
typedef unsigned short ushort8 __attribute__((ext_vector_type(8)));

// adaptive load: f32 flag (wave-uniform) selects fp32 or bf16 interpretation
__device__ __forceinline__ float ldf(const void* p, int i, int f32) {
    if (f32) return ((const float*)p)[i];
    return __bfloat162float(((const __hip_bfloat16*)p)[i]);
}

// per-wave input-dtype detect: fp32 data read as bf16 shows implausible
// magnitudes in ~half the ushorts; bf16 N(0,1) shows none.
__device__ __forceinline__ int detect_f32(const void* x) {
    unsigned short b = ((const unsigned short*)x)[threadIdx.x & 63];
    float v = __uint_as_float(((unsigned int)b) << 16);
    bool bad = !(fabsf(v) < 1000.0f) || (v != 0.0f && fabsf(v) < 1e-15f);
    unsigned long long m = __ballot(bad);
    return (__popcll(m) >= 8) ? 1 : 0;
}

__device__ __forceinline__ const float* uniform_ptr(const float* p) {
    uint64_t v = (uint64_t)p;
    uint32_t lo = __builtin_amdgcn_readfirstlane((uint32_t)v);
    uint32_t hi = __builtin_amdgcn_readfirstlane((uint32_t)(v >> 32));
    return (const float*)(((uint64_t)hi << 32) | lo);
}

// vectorized 16-channel row load (rows are 16B-aligned in both dtypes)
__device__ __forceinline__ void load_row16(const void* x, int n, int f32,
                                           float* dst) {
    if (f32) {
        const floatx4* r = (const floatx4*)((const float*)x + (size_t)n * CDIM);
        #pragma unroll
        for (int t = 0; t < 4; ++t) {
            floatx4 v4 = r[t];
            dst[t * 4 + 0] = v4[0]; dst[t * 4 + 1] = v4[1];
            dst[t * 4 + 2] = v4[2]; dst[t * 4 + 3] = v4[3];
        }
    } else {
        const ushort8* r = (const ushort8*)((const unsigned short*)x + (size_t)n * CDIM);
        #pragma unroll
        for (int t = 0; t < 2; ++t) {
            ushort8 v8 = r[t];
            #pragma unroll
            for (int j = 0; j < 8; ++j)
                dst[t * 8 + j] = __uint_as_float(((unsigned int)v8[j]) << 16);
        }
    }
}

// ---------------- prep: W1 fp32, B-matrix fp16 fragment-packed, q=x@Wq
// (logit scale folded), head=-1 ---------------------------------------------
// Bpk flat index = ((nt*8 + ks)*64 + lane)*8 + j  (one dwordx4 per lane/frag)
//   kk = ks*32 + (lane>>4)*8 + j  -> c = kk>>4, jj = kk&15   (K = (c,j) = 256)
//   nn = nt*16 + (lane&15)        -> net = nn>>7, m = (nn>>3)&15, o = nn&7
__global__ __launch_bounds__(256) void prep_kernel(
    const void* __restrict__ x, const void* __restrict__ Wq,
    const void* __restrict__ Wk1, const void* __restrict__ Wk2,
    const void* __restrict__ Wv1, const void* __restrict__ Wv2,
    float* __restrict__ w1k, float* __restrict__ w1v,
    float* __restrict__ qbuf, _Float16* __restrict__ Bpk,
    int* __restrict__ head, int N)
{
    const int f32 = detect_f32(x);
    int i = blockIdx.x * 256 + threadIdx.x;
    if (i < 160) { w1k[i] = ldf(Wk1, i, f32); w1v[i] = ldf(Wv1, i, f32); }
    if (i < 65536) {
        int j = i & 7, lane = (i >> 3) & 63, ks = (i >> 9) & 7, nt = i >> 12;
        int kk = ks * 32 + (lane >> 4) * 8 + j;
        int nn = nt * 16 + (lane & 15);
        int c = kk >> 4, jj = kk & 15;
        int net = nn >> 7, m = (nn >> 3) & 15, o = nn & 7;
        float v = ldf(net ? Wv2 : Wk2, m * 2048 + c * 128 + jj * 8 + o, f32);
        Bpk[i] = (_Float16)v;
    }
    if (i < N) head[i] = -1;
    if (i < N * 8) {
        int n = i >> 3, o = i & 7;
        float row[CDIM];
        load_row16(x, n, f32, row);
        float acc = 0.0f;
        #pragma unroll
        for (int c = 0; c < CDIM; ++c)
            acc = fmaf(row[c], ldf(Wq, c * DKDIM + o, f32), acc);
        // scale: 1/64 (fcnet+norm) * 1/sqrt(8) (dk), folded here
        qbuf[i] = acc * ((1.0f / 64.0f) * 0.35355339059327373f);
    }
}

// ---------------- edge kernel: geometry -> MFMA GEMM -> per-edge ev/v writes
// block = 256 thr = 4 waves = 64 edges. Wave w owns nt-quarter {4w..4w+3} for
// ALL 64 edges (row-tile pairs share each B fragment). D never hits LDS:
// per-lane h-contraction over nt (m = (2nt + col>>3)&15, o = col&7) then
// shfl_xor(8) merges m-halves; per-net partials combine via small LDS bufs.
// NO fp32 atomics: per-edge ev and v go to global with plain stores; one int
// atomicExch per edge (issued early, consumed late) prepends the edge onto
// its dst node's linked list (head/next).
// smooth_finite basis has compact support: at most 2 of the 10 windows are
// non-zero for any r -> hm waves compute only those 2 (2 exp + 32 FMA,
// was 10 exp + 160 FMA).
__global__ __launch_bounds__(256) void edge_kernel(
    const void* __restrict__ pos, const void* __restrict__ x,
    const int* __restrict__ esrc, const int* __restrict__ edst,
    const float* __restrict__ w1k, const float* __restrict__ w1v,
    const float* __restrict__ qbuf, const _Float16* __restrict__ Bpk,
    int* __restrict__ head, int* __restrict__ next,
    float* __restrict__ evb, _Float16* __restrict__ vbuf, int E)
{
    __shared__ union {
        struct { float xs[64][17]; float sh[64][17]; } g;   // geometry phase
        _Float16 A[16384];            // [r][ks][lane][8] fp16 frags, 32 KB
        struct { float pk[2][64][9]; float pv[2][64][9]; } p; // partial k/v
    } u;
    __shared__ _Float16 hm_lds[64][34];  // [e][net*16 + m]
    __shared__ float cut_lds[64];
    __shared__ int   d_lds[64];

    const int f32  = detect_f32(x);
    const int tid  = threadIdx.x;
    const int lane = tid & 63;
    const int w    = tid >> 6;
    const int q    = lane >> 4;
    const int e0   = blockIdx.x * 64;
    const int e_g  = e0 + lane;
    const int eidx = (e_g < E) ? e_g : (E - 1);
    const int s = esrc[eidx], d = edst[eidx];

    // linked-list prepend: issue atomic now, consume the old head much later
    int prev = -1;
    if (w == 0 && e_g < E) prev = atomicExch(&head[d], e_g);

    // ---- geometry (per-edge work split across the 4 waves) ----
    float vx = ldf(pos, s * 3 + 0, f32) - ldf(pos, d * 3 + 0, f32);
    float vy = ldf(pos, s * 3 + 1, f32) - ldf(pos, d * 3 + 1, f32);
    float vz = ldf(pos, s * 3 + 2, f32) - ldf(pos, d * 3 + 2, f32);
    float r2 = vx * vx + vy * vy + vz * vz;
    float r  = sqrtf(r2 + 1e-18f);          // ref: emb/cutoff radius has +eps

    if (w == 0) {            // spherical harmonics + cutoff + dst
        float rsh = sqrtf(r2);              // ref: SH radius has no eps
        float inv = 1.0f / fmaxf(rsh, 1e-9f);
        float ux = vx * inv, uy = vy * inv, uz = vz * inv;
        const float s3   = 1.7320508075688772f;
        const float s5   = 2.23606797749979f;
        const float s15  = 3.872983346207417f;
        const float c358 = 2.091650066335189f;
        const float c218 = 1.6201851746019651f;
        const float s105 = 10.246950765959598f;
        const float s7h  = 1.3228756555322954f;
        float xx = ux * ux, yy = uy * uy, zz = uz * uz;
        float sh[16];
        sh[0] = 1.0f;
        sh[1] = s3 * ux; sh[2] = s3 * uy; sh[3] = s3 * uz;
        sh[4] = s15 * ux * uy;
        sh[5] = s15 * uy * uz;
        sh[6] = 0.5f * s5 * (3.0f * zz - 1.0f);
        sh[7] = s15 * ux * uz;
        sh[8] = 0.5f * s15 * (xx - yy);
        sh[9] = c358 * uy * (3.0f * xx - yy);
        sh[10] = s105 * ux * uy * uz;
        sh[11] = c218 * uy * (5.0f * zz - 1.0f);
        sh[12] = s7h * uz * (5.0f * zz - 3.0f);
        sh[13] = c218 * ux * (5.0f * zz - 1.0f);
        sh[14] = 0.5f * s105 * uz * (xx - yy);
        sh[15] = c358 * ux * (xx - 3.0f * yy);
        #pragma unroll
        for (int j = 0; j < 16; ++j) u.g.sh[lane][j] = sh[j];
        float tcut = 10.0f * (1.0f - r * (1.0f / 3.5f));
        cut_lds[lane] = (tcut > 0.0f) ? __expf(-1.0f / tcut) : 0.0f;
        d_lds[lane] = d;
    } else if (w == 1) {     // xs gather, vectorized 16B loads
        float row[CDIM];
        load_row16(x, s, f32, row);
        #pragma unroll
        for (int c = 0; c < CDIM; ++c) u.g.xs[lane][c] = row[c];
    } else {                 // w=2: h_k, w=3: h_v (fp16 into hm_lds)
        const float* w1 = uniform_ptr((w == 2) ? w1k : w1v);
        const int off = (w == 2) ? 0 : 16;
        // smooth_finite basis, compact support: windows ia = ib-1 and ib
        const float istep = 11.0f / 3.5f;
        const float coef = (float)(1.14136 * 7.38905609893065 * 3.1622776601683795);
        const float inv_s10 = 0.31622776601683794f;
        float t = r * istep;
        int ib = (int)floorf(t);
        int ia = ib - 1;
        float ua = t - (float)ib;        // u for basis ia, in [0,1)
        float ub = ua - 1.0f;            // u for basis ib, in [-1,0)
        float qa = ua * ua, qb = ub * ub;
        float ea = (ia >= 0 && ia <= 9 && qa < 1.0f)
                   ? coef * __expf(-1.0f / (1.0f - qa)) : 0.0f;
        float eb = (ib >= 0 && ib <= 9 && qb < 1.0f)
                   ? coef * __expf(-1.0f / (1.0f - qb)) : 0.0f;
        ea *= inv_s10; eb *= inv_s10;
        int iac = (ia < 0) ? 0 : ((ia > 9) ? 9 : ia);
        int ibc = (ib < 0) ? 0 : ((ib > 9) ? 9 : ib);
        float rowA[16], rowB[16];
        const floatx4* wa = (const floatx4*)(w1 + iac * 16);
        const floatx4* wb = (const floatx4*)(w1 + ibc * 16);
        #pragma unroll
        for (int tq = 0; tq < 4; ++tq) {
            floatx4 va = wa[tq], vb = wb[tq];
            rowA[tq*4+0]=va[0]; rowA[tq*4+1]=va[1];
            rowA[tq*4+2]=va[2]; rowA[tq*4+3]=va[3];
            rowB[tq*4+0]=vb[0]; rowB[tq*4+1]=vb[1];
            rowB[tq*4+2]=vb[2]; rowB[tq*4+3]=vb[3];
        }
        #pragma unroll
        for (int m = 0; m < 16; ++m) {
            float pre = fmaf(ea, rowA[m], eb * rowB[m]);
            float sig = __builtin_amdgcn_rcpf(1.0f + __expf(-pre));
            hm_lds[lane][off + m] = (_Float16)(pre * sig);
        }
    }
    __syncthreads();

    // ---- A-frag build in regs (wave w -> row-tile r=w) ----
    half8 af[8];
    {
        const int erow = w * 16 + (lane & 15);
        const int coff = q >> 1, jj0 = (q & 1) * 8;
        #pragma unroll
        for (int ks = 0; ks < 8; ++ks) {
            float xsv = u.g.xs[erow][ks * 2 + coff];
            half8 a;
            #pragma unroll
            for (int j = 0; j < 8; ++j)
                a[j] = (_Float16)(xsv * u.g.sh[erow][jj0 + j]);
            af[ks] = a;
        }
    }
    __syncthreads();          // all g reads done -> overlay A
    {
        half8* Af = (half8*)u.A;
        #pragma unroll
        for (int ks = 0; ks < 8; ++ks)
            Af[(w * 8 + ks) * 64 + lane] = af[ks];
    }
    // consume the old head while the atomic result is long since in flight
    if (w == 0 && e_g < E) next[e_g] = prev;
    __syncthreads();

    // ---- GEMM over row-tile pairs + in-register h-contraction ----
    float part[16];           // [r][rr] partial k or v for edge r*16+q*4+rr
    #pragma unroll
    for (int i = 0; i < 16; ++i) part[i] = 0.0f;
    const int b3   = (lane >> 3) & 1;   // col>>3: which m-half this lane holds
    const int moff = (w >> 1) * 16;     // net offset into hm_lds (k=0, v=16)
    const half8* Af = (const half8*)u.A;
    const half8* Bf = (const half8*)Bpk;

    #pragma unroll
    for (int rp = 0; rp < 2; ++rp) {
        half8 a0[8], a1[8];
        #pragma unroll
        for (int ks = 0; ks < 8; ++ks) {
            a0[ks] = Af[((2 * rp)     * 8 + ks) * 64 + lane];
            a1[ks] = Af[((2 * rp + 1) * 8 + ks) * 64 + lane];
        }
        floatx4 acc0[4], acc1[4];
        #pragma unroll
        for (int l = 0; l < 4; ++l) {
            acc0[l] = (floatx4){0.f, 0.f, 0.f, 0.f};
            acc1[l] = (floatx4){0.f, 0.f, 0.f, 0.f};
        }
        #pragma unroll
        for (int l = 0; l < 4; ++l) {
            const int nt = 4 * w + l;
            #pragma unroll
            for (int ks = 0; ks < 8; ++ks) {
                half8 b = Bf[(nt * 8 + ks) * 64 + lane];
                acc0[l] = __builtin_amdgcn_mfma_f32_16x16x32_f16(a0[ks], b, acc0[l], 0, 0, 0);
                acc1[l] = __builtin_amdgcn_mfma_f32_16x16x32_f16(a1[ks], b, acc1[l], 0, 0, 0);
            }
        }
        #pragma unroll
        for (int l = 0; l < 4; ++l) {
            const int m = ((4 * w + l) * 2 + b3) & 15;
            #pragma unroll
            for (int rr = 0; rr < 4; ++rr) {
                const int er = q * 4 + rr;
                part[(2 * rp) * 4 + rr] +=
                    (float)hm_lds[(2 * rp) * 16 + er][moff + m] * acc0[l][rr];
                part[(2 * rp + 1) * 4 + rr] +=
                    (float)hm_lds[(2 * rp + 1) * 16 + er][moff + m] * acc1[l][rr];
            }
        }
    }
    // merge the two m-halves (lanes col and col^8 hold same (e,o))
    #pragma unroll
    for (int i = 0; i < 16; ++i) part[i] += __shfl_xor(part[i], 8, 64);

    __syncthreads();          // A reads done -> overlay partial buffers
    if (b3 == 0) {
        const int o = lane & 7;
        #pragma unroll
        for (int i = 0; i < 16; ++i) {
            const int e = (i >> 2) * 16 + q * 4 + (i & 3);
            if (w < 2) u.p.pk[w][e][o] = part[i];
            else       u.p.pv[w - 2][e][o] = part[i];
        }
    }
    __syncthreads();

    // ---- per-edge ev = cutoff * exp(logit), plain store (no atomics) ----
    if (tid < 64) {
        const int dd = d_lds[tid];
        float logit = 0.0f;
        #pragma unroll
        for (int o = 0; o < 8; ++o) {
            float kv = u.p.pk[0][tid][o] + u.p.pk[1][tid][o];
            logit = fmaf(qbuf[(size_t)dd * 8 + o], kv, logit);  // scale folded
        }
        if (e0 + tid < E)
            evb[e0 + tid] = cut_lds[tid] * expf(logit);   // unstabilized, matches ref
    }

    // ---- per-edge v (1/64 folded), packed fp16x2 stores ----
    {
        const int el = tid & 63, op = tid >> 6;
        if (e0 + el < E) {
            float v0 = u.p.pv[0][el][2 * op]     + u.p.pv[1][el][2 * op];
            float v1 = u.p.pv[0][el][2 * op + 1] + u.p.pv[1][el][2 * op + 1];
            union { _Float16 h[2]; unsigned int b; } pk2;
            pk2.h[0] = (_Float16)(v0 * (1.0f / 64.0f));
            pk2.h[1] = (_Float16)(v1 * (1.0f / 64.0f));
            ((unsigned int*)vbuf)[(size_t)(e0 + el) * 4 + op] = pk2.b;
        }
    }
}

// ---------------- node kernel: single walk of the dst linked list.
// z = sum ev and s = sum sqrt(ev)*v accumulated together; out = s / sqrt(z).
// 8 threads per node (o = 0..7) walk the same list -> loads broadcast.
__global__ __launch_bounds__(256) void node_kernel(
    const float* __restrict__ evb, const _Float16* __restrict__ vbuf,
    const int* __restrict__ head, const int* __restrict__ next,
    void* __restrict__ out, const void* __restrict__ x, int n8)
{
    const int f32 = detect_f32(x);   // full-wave ballot before any divergence
    int i = blockIdx.x * 256 + threadIdx.x;
    if (i >= n8) return;
    const int n = i >> 3, o = i & 7;
    float z = 0.0f, acc = 0.0f;
    for (int e = head[n]; e >= 0; e = next[e]) {
        float ev = evb[e];
        z += ev;
        acc += sqrtf(ev) * (float)vbuf[(size_t)e * 8 + o];
    }
    z = (z == 0.0f) ? 1.0f : z;
    float val = acc / sqrtf(z);
    if (f32) ((float*)out)[i] = val;
    else ((__hip_bfloat16*)out)[i] = __float2bfloat16(val);
}

extern "C" void kernel_launch(void* const* d_in, const int* in_sizes, int n_in,
                              void* d_out, int out_size, void* d_ws, size_t ws_size,
                              hipStream_t stream)
{
    const void* pos = d_in[0];
    const void* x   = d_in[1];
    const void* Wq  = d_in[2];
    const void* Wk1 = d_in[3];
    const void* Wk2 = d_in[4];
    const void* Wv1 = d_in[5];
    const void* Wv2 = d_in[6];
    const int* esrc = (const int*)d_in[7];
    const int* edst = (const int*)d_in[8];
    const int N = in_sizes[1] / CDIM;
    const int E = in_sizes[7];

    // workspace layout (Bpk first for 16B alignment of half8 loads)
    _Float16* Bpk = (_Float16*)d_ws;                       // 65536 fp16
    float* w1k  = (float*)(Bpk + 65536);                   // 160
    float* w1v  = w1k + 160;                               // 160
    float* qbuf = w1v + 160;                               // N*8
    float* evb  = qbuf + (size_t)N * 8;                    // E
    _Float16* vbuf = (_Float16*)(evb + E);                 // E*8 fp16
    int*   head = (int*)(vbuf + (size_t)E * 8);            // N
    int*   next = head + N;                                // E

    int prep_threads = N * 8 > 65536 ? N * 8 : 65536;
    int prep_blocks = (prep_threads + 255) / 256;
    prep_kernel<<<prep_blocks, 256, 0, stream>>>(x, Wq, Wk1, Wk2, Wv1, Wv2,
                                                 w1k, w1v, qbuf, Bpk, head, N);

    int edge_blocks = (E + 63) / 64;
    edge_kernel<<<edge_blocks, 256, 0, stream>>>(pos, x, esrc, edst,
                                                 w1k, w1v, qbuf, Bpk,
                                                 head, next, evb, vbuf, E);

    node_kernel<<<(N * 8 + 255) / 256, 256, 0, stream>>>(
        evb, vbuf, head, next, d_out, x, N * 8);
}

// Round 7
// 95.857 us; speedup vs baseline: 1.1626x; 1.0038x over previous
//
#include <hip/hip_runtime.h>
#include <hip/hip_bf16.h>

#define NBASIS 10
#define CDIM 16
#define DKDIM 8
#define JDIM 16

typedef _Float16 half8 __attribute__((ext_vector_type(8)));
typedef float floatx4 __attribute__((ext_vector_type(4)));
typedef unsigned short ushort8 __attribute__((ext_vector_type(8)));

// adaptive load: f32 flag (wave-uniform) selects fp32 or bf16 interpretation
__device__ __forceinline__ float ldf(const void* p, int i, int f32) {
    if (f32) return ((const float*)p)[i];
    return __bfloat162float(((const __hip_bfloat16*)p)[i]);
}

// per-wave input-dtype detect: fp32 data read as bf16 shows implausible
// magnitudes in ~half the ushorts; bf16 N(0,1) shows none.
__device__ __forceinline__ int detect_f32(const void* x) {
    unsigned short b = ((const unsigned short*)x)[threadIdx.x & 63];
    float v = __uint_as_float(((unsigned int)b) << 16);
    bool bad = !(fabsf(v) < 1000.0f) || (v != 0.0f && fabsf(v) < 1e-15f);
    unsigned long long m = __ballot(bad);
    return (__popcll(m) >= 8) ? 1 : 0;
}

__device__ __forceinline__ const float* uniform_ptr(const float* p) {
    uint64_t v = (uint64_t)p;
    uint32_t lo = __builtin_amdgcn_readfirstlane((uint32_t)v);
    uint32_t hi = __builtin_amdgcn_readfirstlane((uint32_t)(v >> 32));
    return (const float*)(((uint64_t)hi << 32) | lo);
}

// vectorized 16-channel row load (rows are 16B-aligned in both dtypes)
__device__ __forceinline__ void load_row16(const void* x, int n, int f32,
                                           float* dst) {
    if (f32) {
        const floatx4* r = (const floatx4*)((const float*)x + (size_t)n * CDIM);
        #pragma unroll
        for (int t = 0; t < 4; ++t) {
            floatx4 v4 = r[t];
            dst[t * 4 + 0] = v4[0]; dst[t * 4 + 1] = v4[1];
            dst[t * 4 + 2] = v4[2]; dst[t * 4 + 3] = v4[3];
        }
    } else {
        const ushort8* r = (const ushort8*)((const unsigned short*)x + (size_t)n * CDIM);
        #pragma unroll
        for (int t = 0; t < 2; ++t) {
            ushort8 v8 = r[t];
            #pragma unroll
            for (int j = 0; j < 8; ++j)
                dst[t * 8 + j] = __uint_as_float(((unsigned int)v8[j]) << 16);
        }
    }
}

// ---------------- prep: W1 fp32, B-matrix fp16 fragment-packed, q=x@Wq
// (logit scale folded), head=-1 ---------------------------------------------
// Bpk dest = ((nt*8 + ks)*64 + lane)*8 + j with
//   kk = ks*32 + (lane>>4)*8 + j  (= c*16 + jj, the K index)
//   nn = nt*16 + (lane&15)        (= net*128 + m*8 + o, the N index)
// This kernel iterates SOURCE-linearly (coalesced reads from Wk2/Wv2) and
// scatters the 2B stores: i = net*32768 + m*2048 + c*128 + jj*8 + o.
__global__ __launch_bounds__(256) void prep_kernel(
    const void* __restrict__ x, const void* __restrict__ Wq,
    const void* __restrict__ Wk1, const void* __restrict__ Wk2,
    const void* __restrict__ Wv1, const void* __restrict__ Wv2,
    float* __restrict__ w1k, float* __restrict__ w1v,
    float* __restrict__ qbuf, _Float16* __restrict__ Bpk,
    int* __restrict__ head, int N)
{
    const int f32 = detect_f32(x);
    int i = blockIdx.x * 256 + threadIdx.x;
    if (i < 160) { w1k[i] = ldf(Wk1, i, f32); w1v[i] = ldf(Wv1, i, f32); }
    if (i < 65536) {
        int net = i >> 15;
        int o = i & 7, jj = (i >> 3) & 15, c = (i >> 7) & 15, m = (i >> 11) & 15;
        float v = ldf(net ? Wv2 : Wk2, i & 32767, f32);   // coalesced
        int kk = c * 16 + jj;
        int nn = net * 128 + m * 8 + o;
        int ks = kk >> 5, lane_hi = (kk >> 3) & 3, j = kk & 7;
        int nt = nn >> 4, lane_lo = nn & 15;
        int lane = lane_hi * 16 + lane_lo;
        Bpk[((nt * 8 + ks) * 64 + lane) * 8 + j] = (_Float16)v;
    }
    if (i < N) head[i] = -1;
    if (i < N * 8) {
        int n = i >> 3, o = i & 7;
        float row[CDIM];
        load_row16(x, n, f32, row);
        float acc = 0.0f;
        #pragma unroll
        for (int c = 0; c < CDIM; ++c)
            acc = fmaf(row[c], ldf(Wq, c * DKDIM + o, f32), acc);
        // scale: 1/64 (fcnet+norm) * 1/sqrt(8) (dk), folded here
        qbuf[i] = acc * ((1.0f / 64.0f) * 0.35355339059327373f);
    }
}

// ---------------- edge kernel: geometry -> MFMA GEMM -> per-edge ev/v writes
// block = 256 thr = 4 waves = 64 edges. Wave w owns nt-quarter {4w..4w+3} for
// ALL 64 edges (row-tile pairs share each B fragment). D never hits LDS:
// per-lane h-contraction over nt (m = (2nt + col>>3)&15, o = col&7) then
// shfl_xor(8) merges m-halves; per-net partials combine via small LDS bufs.
// NO fp32 atomics: per-edge ev and v go to global with plain stores; one int
// atomicExch per edge (issued early, consumed late) prepends the edge onto
// its dst node's linked list (head/next).
// smooth_finite basis has compact support: at most 2 of the 10 windows are
// non-zero for any r -> hm waves compute only those 2 (2 exp + 32 FMA).
__global__ __launch_bounds__(256) void edge_kernel(
    const void* __restrict__ pos, const void* __restrict__ x,
    const int* __restrict__ esrc, const int* __restrict__ edst,
    const float* __restrict__ w1k, const float* __restrict__ w1v,
    const float* __restrict__ qbuf, const _Float16* __restrict__ Bpk,
    int* __restrict__ head, int* __restrict__ next,
    float* __restrict__ evb, _Float16* __restrict__ vbuf, int E)
{
    __shared__ union {
        struct { float xs[64][17]; float sh[64][17]; } g;   // geometry phase
        _Float16 A[16384];            // [r][ks][lane][8] fp16 frags, 32 KB
        struct { float pk[2][64][9]; float pv[2][64][9]; } p; // partial k/v
    } u;
    __shared__ _Float16 hm_lds[64][34];  // [e][net*16 + m]
    __shared__ float cut_lds[64];
    __shared__ int   d_lds[64];

    const int f32  = detect_f32(x);
    const int tid  = threadIdx.x;
    const int lane = tid & 63;
    const int w    = tid >> 6;
    const int q    = lane >> 4;
    const int e0   = blockIdx.x * 64;
    const int e_g  = e0 + lane;
    const int eidx = (e_g < E) ? e_g : (E - 1);
    const int s = esrc[eidx], d = edst[eidx];

    // linked-list prepend: issue atomic now, consume the old head much later
    int prev = -1;
    if (w == 0 && e_g < E) prev = atomicExch(&head[d], e_g);

    // ---- geometry (per-edge work split across the 4 waves) ----
    float vx = ldf(pos, s * 3 + 0, f32) - ldf(pos, d * 3 + 0, f32);
    float vy = ldf(pos, s * 3 + 1, f32) - ldf(pos, d * 3 + 1, f32);
    float vz = ldf(pos, s * 3 + 2, f32) - ldf(pos, d * 3 + 2, f32);
    float r2 = vx * vx + vy * vy + vz * vz;
    float r  = sqrtf(r2 + 1e-18f);          // ref: emb/cutoff radius has +eps

    if (w == 0) {            // spherical harmonics + cutoff + dst
        float rsh = sqrtf(r2);              // ref: SH radius has no eps
        float inv = 1.0f / fmaxf(rsh, 1e-9f);
        float ux = vx * inv, uy = vy * inv, uz = vz * inv;
        const float s3   = 1.7320508075688772f;
        const float s5   = 2.23606797749979f;
        const float s15  = 3.872983346207417f;
        const float c358 = 2.091650066335189f;
        const float c218 = 1.6201851746019651f;
        const float s105 = 10.246950765959598f;
        const float s7h  = 1.3228756555322954f;
        float xx = ux * ux, yy = uy * uy, zz = uz * uz;
        float sh[16];
        sh[0] = 1.0f;
        sh[1] = s3 * ux; sh[2] = s3 * uy; sh[3] = s3 * uz;
        sh[4] = s15 * ux * uy;
        sh[5] = s15 * uy * uz;
        sh[6] = 0.5f * s5 * (3.0f * zz - 1.0f);
        sh[7] = s15 * ux * uz;
        sh[8] = 0.5f * s15 * (xx - yy);
        sh[9] = c358 * uy * (3.0f * xx - yy);
        sh[10] = s105 * ux * uy * uz;
        sh[11] = c218 * uy * (5.0f * zz - 1.0f);
        sh[12] = s7h * uz * (5.0f * zz - 3.0f);
        sh[13] = c218 * ux * (5.0f * zz - 1.0f);
        sh[14] = 0.5f * s105 * uz * (xx - yy);
        sh[15] = c358 * ux * (xx - 3.0f * yy);
        #pragma unroll
        for (int j = 0; j < 16; ++j) u.g.sh[lane][j] = sh[j];
        float tcut = 10.0f * (1.0f - r * (1.0f / 3.5f));
        cut_lds[lane] = (tcut > 0.0f) ? __expf(-1.0f / tcut) : 0.0f;
        d_lds[lane] = d;
    } else if (w == 1) {     // xs gather, vectorized 16B loads
        float row[CDIM];
        load_row16(x, s, f32, row);
        #pragma unroll
        for (int c = 0; c < CDIM; ++c) u.g.xs[lane][c] = row[c];
    } else {                 // w=2: h_k, w=3: h_v (fp16 into hm_lds)
        const float* w1 = uniform_ptr((w == 2) ? w1k : w1v);
        const int off = (w == 2) ? 0 : 16;
        // smooth_finite basis, compact support: windows ia = ib-1 and ib
        const float istep = 11.0f / 3.5f;
        const float coef = (float)(1.14136 * 7.38905609893065 * 3.1622776601683795);
        const float inv_s10 = 0.31622776601683794f;
        float t = r * istep;
        int ib = (int)floorf(t);
        int ia = ib - 1;
        float ua = t - (float)ib;        // u for basis ia, in [0,1)
        float ub = ua - 1.0f;            // u for basis ib, in [-1,0)
        float qa = ua * ua, qb = ub * ub;
        float ea = (ia >= 0 && ia <= 9 && qa < 1.0f)
                   ? coef * __expf(-1.0f / (1.0f - qa)) : 0.0f;
        float eb = (ib >= 0 && ib <= 9 && qb < 1.0f)
                   ? coef * __expf(-1.0f / (1.0f - qb)) : 0.0f;
        ea *= inv_s10; eb *= inv_s10;
        int iac = (ia < 0) ? 0 : ((ia > 9) ? 9 : ia);
        int ibc = (ib < 0) ? 0 : ((ib > 9) ? 9 : ib);
        float rowA[16], rowB[16];
        const floatx4* wa = (const floatx4*)(w1 + iac * 16);
        const floatx4* wb = (const floatx4*)(w1 + ibc * 16);
        #pragma unroll
        for (int tq = 0; tq < 4; ++tq) {
            floatx4 va = wa[tq], vb = wb[tq];
            rowA[tq*4+0]=va[0]; rowA[tq*4+1]=va[1];
            rowA[tq*4+2]=va[2]; rowA[tq*4+3]=va[3];
            rowB[tq*4+0]=vb[0]; rowB[tq*4+1]=vb[1];
            rowB[tq*4+2]=vb[2]; rowB[tq*4+3]=vb[3];
        }
        #pragma unroll
        for (int m = 0; m < 16; ++m) {
            float pre = fmaf(ea, rowA[m], eb * rowB[m]);
            float sig = __builtin_amdgcn_rcpf(1.0f + __expf(-pre));
            hm_lds[lane][off + m] = (_Float16)(pre * sig);
        }
    }
    __syncthreads();

    // ---- A-frag build in regs (wave w -> row-tile r=w) ----
    half8 af[8];
    {
        const int erow = w * 16 + (lane & 15);
        const int coff = q >> 1, jj0 = (q & 1) * 8;
        #pragma unroll
        for (int ks = 0; ks < 8; ++ks) {
            float xsv = u.g.xs[erow][ks * 2 + coff];
            half8 a;
            #pragma unroll
            for (int j = 0; j < 8; ++j)
                a[j] = (_Float16)(xsv * u.g.sh[erow][jj0 + j]);
            af[ks] = a;
        }
    }
    __syncthreads();          // all g reads done -> overlay A
    {
        half8* Af = (half8*)u.A;
        #pragma unroll
        for (int ks = 0; ks < 8; ++ks)
            Af[(w * 8 + ks) * 64 + lane] = af[ks];
    }
    // consume the old head while the atomic result is long since in flight
    if (w == 0 && e_g < E) next[e_g] = prev;
    __syncthreads();

    // ---- GEMM over row-tile pairs + in-register h-contraction ----
    float part[16];           // [r][rr] partial k or v for edge r*16+q*4+rr
    #pragma unroll
    for (int i = 0; i < 16; ++i) part[i] = 0.0f;
    const int b3   = (lane >> 3) & 1;   // col>>3: which m-half this lane holds
    const int moff = (w >> 1) * 16;     // net offset into hm_lds (k=0, v=16)
    const half8* Af = (const half8*)u.A;
    const half8* Bf = (const half8*)Bpk;

    #pragma unroll
    for (int rp = 0; rp < 2; ++rp) {
        half8 a0[8], a1[8];
        #pragma unroll
        for (int ks = 0; ks < 8; ++ks) {
            a0[ks] = Af[((2 * rp)     * 8 + ks) * 64 + lane];
            a1[ks] = Af[((2 * rp + 1) * 8 + ks) * 64 + lane];
        }
        floatx4 acc0[4], acc1[4];
        #pragma unroll
        for (int l = 0; l < 4; ++l) {
            acc0[l] = (floatx4){0.f, 0.f, 0.f, 0.f};
            acc1[l] = (floatx4){0.f, 0.f, 0.f, 0.f};
        }
        #pragma unroll
        for (int l = 0; l < 4; ++l) {
            const int nt = 4 * w + l;
            #pragma unroll
            for (int ks = 0; ks < 8; ++ks) {
                half8 b = Bf[(nt * 8 + ks) * 64 + lane];
                acc0[l] = __builtin_amdgcn_mfma_f32_16x16x32_f16(a0[ks], b, acc0[l], 0, 0, 0);
                acc1[l] = __builtin_amdgcn_mfma_f32_16x16x32_f16(a1[ks], b, acc1[l], 0, 0, 0);
            }
        }
        #pragma unroll
        for (int l = 0; l < 4; ++l) {
            const int m = ((4 * w + l) * 2 + b3) & 15;
            #pragma unroll
            for (int rr = 0; rr < 4; ++rr) {
                const int er = q * 4 + rr;
                part[(2 * rp) * 4 + rr] +=
                    (float)hm_lds[(2 * rp) * 16 + er][moff + m] * acc0[l][rr];
                part[(2 * rp + 1) * 4 + rr] +=
                    (float)hm_lds[(2 * rp + 1) * 16 + er][moff + m] * acc1[l][rr];
            }
        }
    }
    // merge the two m-halves (lanes col and col^8 hold same (e,o))
    #pragma unroll
    for (int i = 0; i < 16; ++i) part[i] += __shfl_xor(part[i], 8, 64);

    __syncthreads();          // A reads done -> overlay partial buffers
    if (b3 == 0) {
        const int o = lane & 7;
        #pragma unroll
        for (int i = 0; i < 16; ++i) {
            const int e = (i >> 2) * 16 + q * 4 + (i & 3);
            if (w < 2) u.p.pk[w][e][o] = part[i];
            else       u.p.pv[w - 2][e][o] = part[i];
        }
    }
    __syncthreads();

    // ---- per-edge ev = cutoff * exp(logit), plain store (no atomics) ----
    if (tid < 64) {
        const int dd = d_lds[tid];
        const floatx4* qp = (const floatx4*)(qbuf + (size_t)dd * 8);
        floatx4 q0 = qp[0], q1 = qp[1];
        float logit = 0.0f;
        #pragma unroll
        for (int o = 0; o < 4; ++o) {
            float kv0 = u.p.pk[0][tid][o]     + u.p.pk[1][tid][o];
            float kv1 = u.p.pk[0][tid][o + 4] + u.p.pk[1][tid][o + 4];
            logit = fmaf(q0[o], kv0, logit);
            logit = fmaf(q1[o], kv1, logit);
        }
        if (e0 + tid < E)
            evb[e0 + tid] = cut_lds[tid] * __expf(logit);  // scale pre-folded in q
    }

    // ---- per-edge v (1/64 folded), packed fp16x2 stores ----
    {
        const int el = tid & 63, op = tid >> 6;
        if (e0 + el < E) {
            float v0 = u.p.pv[0][el][2 * op]     + u.p.pv[1][el][2 * op];
            float v1 = u.p.pv[0][el][2 * op + 1] + u.p.pv[1][el][2 * op + 1];
            union { _Float16 h[2]; unsigned int b; } pk2;
            pk2.h[0] = (_Float16)(v0 * (1.0f / 64.0f));
            pk2.h[1] = (_Float16)(v1 * (1.0f / 64.0f));
            ((unsigned int*)vbuf)[(size_t)(e0 + el) * 4 + op] = pk2.b;
        }
    }
}

// ---------------- node kernel: single walk of the dst linked list.
// z = sum ev and s = sum sqrt(ev)*v accumulated together; out = s / sqrt(z).
// 4 threads per node (t = 0..3), each handling 2 output dims via the packed
// fp16x2 words -> half the walk instructions of the 8-lane version.
__global__ __launch_bounds__(256) void node_kernel(
    const float* __restrict__ evb, const unsigned int* __restrict__ vbuf32,
    const int* __restrict__ head, const int* __restrict__ next,
    void* __restrict__ out, const void* __restrict__ x, int n4)
{
    const int f32 = detect_f32(x);   // full-wave ballot before any divergence
    int i = blockIdx.x * 256 + threadIdx.x;
    if (i >= n4) return;
    const int n = i >> 2, t = i & 3;
    float z = 0.0f, a0 = 0.0f, a1 = 0.0f;
    for (int e = head[n]; e >= 0; e = next[e]) {
        float ev = evb[e];
        float se = sqrtf(ev);
        union { unsigned int b; _Float16 h[2]; } uu;
        uu.b = vbuf32[(size_t)e * 4 + t];
        z += ev;
        a0 += se * (float)uu.h[0];
        a1 += se * (float)uu.h[1];
    }
    z = (z == 0.0f) ? 1.0f : z;
    float sq = sqrtf(z);
    float v0 = a0 / sq, v1 = a1 / sq;
    if (f32) {
        float2 val; val.x = v0; val.y = v1;
        ((float2*)out)[(size_t)n * 4 + t] = val;
    } else {
        __hip_bfloat16 b0 = __float2bfloat16(v0), b1 = __float2bfloat16(v1);
        unsigned int pk = ((unsigned int)(*(unsigned short*)&b1) << 16)
                        | (unsigned int)(*(unsigned short*)&b0);
        ((unsigned int*)out)[(size_t)n * 4 + t] = pk;
    }
}

extern "C" void kernel_launch(void* const* d_in, const int* in_sizes, int n_in,
                              void* d_out, int out_size, void* d_ws, size_t ws_size,
                              hipStream_t stream)
{
    const void* pos = d_in[0];
    const void* x   = d_in[1];
    const void* Wq  = d_in[2];
    const void* Wk1 = d_in[3];
    const void* Wk2 = d_in[4];
    const void* Wv1 = d_in[5];
    const void* Wv2 = d_in[6];
    const int* esrc = (const int*)d_in[7];
    const int* edst = (const int*)d_in[8];
    const int N = in_sizes[1] / CDIM;
    const int E = in_sizes[7];

    // workspace layout (Bpk first for 16B alignment of half8 loads)
    _Float16* Bpk = (_Float16*)d_ws;                       // 65536 fp16
    float* w1k  = (float*)(Bpk + 65536);                   // 160
    float* w1v  = w1k + 160;                               // 160
    float* qbuf = w1v + 160;                               // N*8
    float* evb  = qbuf + (size_t)N * 8;                    // E
    _Float16* vbuf = (_Float16*)(evb + E);                 // E*8 fp16
    int*   head = (int*)(vbuf + (size_t)E * 8);            // N
    int*   next = head + N;                                // E

    int prep_threads = N * 8 > 65536 ? N * 8 : 65536;
    int prep_blocks = (prep_threads + 255) / 256;
    prep_kernel<<<prep_blocks, 256, 0, stream>>>(x, Wq, Wk1, Wk2, Wv1, Wv2,
                                                 w1k, w1v, qbuf, Bpk, head, N);

    int edge_blocks = (E + 63) / 64;
    edge_kernel<<<edge_blocks, 256, 0, stream>>>(pos, x, esrc, edst,
                                                 w1k, w1v, qbuf, Bpk,
                                                 head, next, evb, vbuf, E);

    node_kernel<<<(N * 4 + 255) / 256, 256, 0, stream>>>(
        evb, (const unsigned int*)vbuf, head, next, d_out, x, N * 4);
}